// Round 2
// baseline (5675.350 us; speedup 1.0000x reference)
//
#include <hip/hip_runtime.h>
#include <hip/hip_bf16.h>

#define BB 128
#define SS 1024
#define HH 128
#define G3 384

typedef __hip_bfloat16 bf16;

__device__ __forceinline__ float blo(unsigned u) { return __uint_as_float(u << 16); }
__device__ __forceinline__ float bhi(unsigned u) { return __uint_as_float(u & 0xffff0000u); }
__device__ __forceinline__ float leaky(float x) { return x >= 0.f ? x : 0.01f * x; }

// ---- dtype-agnostic load/store -------------------------------------------
template <bool F32>
__device__ __forceinline__ float LD(const void* p, size_t i) {
  if (F32) return ((const float*)p)[i];
  return __bfloat162float(((const bf16*)p)[i]);
}
template <bool F32>
__device__ __forceinline__ void ST(void* p, size_t i, float v) {
  if (F32) ((float*)p)[i] = v;
  else ((bf16*)p)[i] = __float2bfloat16(v);
}

// ---- runtime dtype sniffer (wave-uniform) --------------------------------
// True bf16 N(0,1) data: exponent fields cluster near 127, never extreme.
// fp32 data read as bf16 halfwords: even halfwords are mantissa junk with
// ~uniform exponent fields -> many extremes.
__device__ __forceinline__ bool sniff_f32(const void* obs) {
  const int l = threadIdx.x & 63;
  const unsigned short* h = (const unsigned short*)obs;
  unsigned a = h[2 * l], b = h[2 * l + 1];
  unsigned ea = (a >> 7) & 0xFFu, eb = (b >> 7) & 0xFFu;
  bool ja = (ea >= 0xC8u) || (ea > 0u && ea <= 0x30u);
  bool jb = (eb >= 0xC8u) || (eb > 0u && eb <= 0x30u);
  int junk = __popcll(__ballot(ja)) + __popcll(__ballot(jb));
  return junk >= 10;
}

// dot of K floats (LDS) with K weights (global, scalar loads)
template <bool F32, int K>
__device__ __forceinline__ float dotg(const float* xl, const void* w, size_t off, float acc) {
#pragma unroll
  for (int i = 0; i < K; ++i) acc += xl[i] * LD<F32>(w, off + i);
  return acc;
}

// ---------------- Phase 1: per-token pre-GRU -------------------------------
template <bool F32>
__device__ void pre_body(const void* obs, const void* me_w1, const void* me_b1,
                         const void* me_w2, const void* me_b2, const void* ae_w1,
                         const void* ae_b1, const void* ae_w2, const void* ae_b2,
                         const void* ipw, const void* ipb, const void* opw,
                         const void* opb, const void* lng, const void* lnb,
                         const void* wih, const void* bih, bf16* xp_out,
                         float* u, int wid, int l, size_t token) {
  // LDS map (per wave, 480 floats):
  // 0..31 t1_m1 | 32..63 t1_m2 | 64..95 t1_ac   [later 0..63 CTX, 64..127 XN]
  // 96 M1E | 160 M2E | 224 ACE | 288 Q | 352 K1 | 416 K2
  const size_t ob = token * 12;

  // stage 1: encoder hidden layers
  {
    const int half = l >> 5;  // 0 -> m1, 1 -> m2
    float i0 = LD<F32>(obs, ob + 3 * half + 0);
    float i1 = LD<F32>(obs, ob + 3 * half + 1);
    float i2 = LD<F32>(obs, ob + 3 * half + 2);
    const int row = l & 31;
    float acc = LD<F32>(me_b1, row);
    acc += i0 * LD<F32>(me_w1, row * 3 + 0);
    acc += i1 * LD<F32>(me_w1, row * 3 + 1);
    acc += i2 * LD<F32>(me_w1, row * 3 + 2);
    u[l] = leaky(acc);
    if (l < 32) {
      float a2 = LD<F32>(ae_b1, l);
#pragma unroll
      for (int j = 0; j < 6; ++j) a2 += LD<F32>(obs, ob + 6 + j) * LD<F32>(ae_w1, l * 6 + j);
      u[64 + l] = leaky(a2);
    }
  }
  __syncthreads();

  // stage 2: encoder output layers
  float m1e = dotg<F32, 32>(u + 0, me_w2, (size_t)l * 32, LD<F32>(me_b2, l));
  float m2e = dotg<F32, 32>(u + 32, me_w2, (size_t)l * 32, LD<F32>(me_b2, l));
  float ace = dotg<F32, 32>(u + 64, ae_w2, (size_t)l * 32, LD<F32>(ae_b2, l));
  u[96 + l] = m1e;
  u[160 + l] = m2e;
  u[224 + l] = ace;
  __syncthreads();

  // stage 3: q, k1, k2, v1, v2
  float q = dotg<F32, 64>(u + 224, ipw, (size_t)l * 64, LD<F32>(ipb, l));
  float k1 = dotg<F32, 64>(u + 96, ipw, (size_t)(64 + l) * 64, LD<F32>(ipb, 64 + l));
  float k2 = dotg<F32, 64>(u + 160, ipw, (size_t)(64 + l) * 64, LD<F32>(ipb, 64 + l));
  float v1 = dotg<F32, 64>(u + 96, ipw, (size_t)(128 + l) * 64, LD<F32>(ipb, 128 + l));
  float v2 = dotg<F32, 64>(u + 160, ipw, (size_t)(128 + l) * 64, LD<F32>(ipb, 128 + l));
  u[288 + l] = q;
  u[352 + l] = k1;
  u[416 + l] = k2;
  __syncthreads();

  // stage 4: 2-key attention per head (HD=16)
  {
    const int hd = l >> 4;
    float s1 = 0.f, s2 = 0.f;
#pragma unroll
    for (int d = 0; d < 16; ++d) {
      float qq = u[288 + hd * 16 + d];
      s1 += qq * u[352 + hd * 16 + d];
      s2 += qq * u[416 + hd * 16 + d];
    }
    s1 *= 0.25f;
    s2 *= 0.25f;
    float mx = fmaxf(s1, s2);
    float e1 = __expf(s1 - mx), e2 = __expf(s2 - mx);
    float a1 = e1 / (e1 + e2);
    u[l] = a1 * v1 + (1.f - a1) * v2;  // CTX
  }
  __syncthreads();

  // out_proj + residual + LayerNorm
  float ao = dotg<F32, 64>(u + 0, opw, (size_t)l * 64, LD<F32>(opb, l));
  float x = ao + ace;
  float s = x, s2s = x * x;
#pragma unroll
  for (int off = 32; off; off >>= 1) {
    s += __shfl_xor(s, off);
    s2s += __shfl_xor(s2s, off);
  }
  float mu = s * (1.f / 64.f);
  float var = s2s * (1.f / 64.f) - mu * mu;
  float rs = rsqrtf(var + 1e-5f);
  float xn = (x - mu) * rs * LD<F32>(lng, l) + LD<F32>(lnb, l);
  u[64 + l] = xn;  // XN
  __syncthreads();

  // stage 5: xp = xn @ W_ih.T + b_ih (384 outs, 6 per lane), stored bf16
  const size_t base = token * G3;
#pragma unroll
  for (int r = 0; r < 6; ++r) {
    int j = r * 64 + l;
    float acc = dotg<F32, 64>(u + 64, wih, (size_t)j * 64, LD<F32>(bih, j));
    xp_out[base + j] = __float2bfloat16(acc);
  }
}

__global__ __launch_bounds__(256) void pre_kernel(
    const void* obs, const void* me_w1, const void* me_b1, const void* me_w2,
    const void* me_b2, const void* ae_w1, const void* ae_b1, const void* ae_w2,
    const void* ae_b2, const void* ipw, const void* ipb, const void* opw,
    const void* opb, const void* lng, const void* lnb, const void* wih,
    const void* bih, bf16* xp_out) {
  __shared__ __align__(16) float sb[4 * 480];
  const int wid = threadIdx.x >> 6;
  const int l = threadIdx.x & 63;
  const size_t token = (size_t)blockIdx.x * 4 + wid;
  float* u = &sb[wid * 480];
  if (sniff_f32(obs))
    pre_body<true>(obs, me_w1, me_b1, me_w2, me_b2, ae_w1, ae_b1, ae_w2, ae_b2,
                   ipw, ipb, opw, opb, lng, lnb, wih, bih, xp_out, u, wid, l, token);
  else
    pre_body<false>(obs, me_w1, me_b1, me_w2, me_b2, ae_w1, ae_b1, ae_w2, ae_b2,
                    ipw, ipb, opw, opb, lng, lnb, wih, bih, xp_out, u, wid, l, token);
}

// ---------------- Phase 2: sequential GRU ----------------------------------
template <bool F32>
__device__ void gru_body(const bf16* xp, const void* hs, const void* whh,
                         const void* bhh, bf16* gout, void* d_out, float* hl,
                         float* hp, float* xq) {
  const int j = threadIdx.x;
  const int b = blockIdx.x;

  // thread j caches W_hh row j as 64 packed bf16-pair words (scalar 4B loads)
  unsigned w[64];
  if (F32) {
    const float* wf = (const float*)whh + (size_t)j * HH;
#pragma unroll
    for (int i = 0; i < 64; ++i) {
      unsigned lo = __float_as_uint(wf[2 * i]) >> 16;
      unsigned hi = __float_as_uint(wf[2 * i + 1]) >> 16;
      w[i] = lo | (hi << 16);
    }
  } else {
    const unsigned* ws = (const unsigned*)whh + (size_t)j * 64;
#pragma unroll
    for (int i = 0; i < 64; ++i) w[i] = ws[i];
  }
  const float bias = LD<F32>(bhh, j);
  if (j < HH) hl[j] = LD<F32>(hs, b * HH + j);
  __syncthreads();

  const bf16* xrow = xp + (size_t)b * SS * G3 + j;
  bf16* grow = gout + (size_t)b * SS * HH;

  for (int t = 0; t < SS; ++t) {
    float xv = __bfloat162float(xrow[(size_t)t * G3]);
    float acc = bias;
    const float4* h4 = (const float4*)hl;
#pragma unroll
    for (int i = 0; i < 32; ++i) {
      float4 hv = h4[i];
      unsigned wa = w[2 * i], wb = w[2 * i + 1];
      acc += hv.x * blo(wa) + hv.y * bhi(wa) + hv.z * blo(wb) + hv.w * bhi(wb);
    }
    hp[j] = acc;
    xq[j] = xv;
    __syncthreads();
    if (j < HH) {
      float r = 1.f / (1.f + __expf(-(xq[j] + hp[j])));
      float z = 1.f / (1.f + __expf(-(xq[HH + j] + hp[HH + j])));
      float gp = xq[2 * HH + j] + r * hp[2 * HH + j];
      float e = __expf(-2.f * fabsf(gp));
      float th = copysignf((1.f - e) / (1.f + e), gp);
      float hn = (1.f - z) * th + z * hl[j];
      hl[j] = hn;
      grow[(size_t)t * HH + j] = __float2bfloat16(hn);
    }
    __syncthreads();
  }
  if (j < HH) ST<F32>(d_out, (size_t)BB * SS + b * HH + j, hl[j]);
}

__global__ __launch_bounds__(384) void gru_kernel(const void* obs, const bf16* xp,
                                                  const void* hs, const void* whh,
                                                  const void* bhh, bf16* gout,
                                                  void* d_out) {
  __shared__ __align__(16) float hl[HH];
  __shared__ float hp[G3];
  __shared__ float xq[G3];
  if (sniff_f32(obs)) gru_body<true>(xp, hs, whh, bhh, gout, d_out, hl, hp, xq);
  else gru_body<false>(xp, hs, whh, bhh, gout, d_out, hl, hp, xq);
}

// ---------------- Phase 3: token-parallel MLP head -------------------------
template <bool F32>
__device__ void mlp_body(const bf16* gru, const void* w0, const void* b0,
                         const void* w1, const void* b1, const void* ow,
                         const void* ob, void* d_out, float* g, float* f0,
                         float* red) {
  const int i = threadIdx.x;
  const size_t token = blockIdx.x;

  g[i] = __bfloat162float(gru[token * HH + i]);
  __syncthreads();
  float a0 = leaky(dotg<F32, 128>(g, w0, (size_t)i * HH, LD<F32>(b0, i)));
  f0[i] = a0;
  __syncthreads();
  float a1 = leaky(dotg<F32, 128>(f0, w1, (size_t)i * HH, LD<F32>(b1, i)));
  float p = a1 * LD<F32>(ow, i);
#pragma unroll
  for (int off = 32; off; off >>= 1) p += __shfl_xor(p, off);
  if ((i & 63) == 0) red[i >> 6] = p;
  __syncthreads();
  if (i == 0) ST<F32>(d_out, token, red[0] + red[1] + LD<F32>(ob, 0));
}

__global__ __launch_bounds__(128) void mlp_kernel(const void* obs, const bf16* gru,
                                                  const void* w0, const void* b0,
                                                  const void* w1, const void* b1,
                                                  const void* ow, const void* ob,
                                                  void* d_out) {
  __shared__ __align__(16) float g[HH];
  __shared__ __align__(16) float f0[HH];
  __shared__ float red[2];
  if (sniff_f32(obs)) mlp_body<true>(gru, w0, b0, w1, b1, ow, ob, d_out, g, f0, red);
  else mlp_body<false>(gru, w0, b0, w1, b1, ow, ob, d_out, g, f0, red);
}

// ws-too-small sentinel: fill out with ~999 (visible under bf16 or fp32 decode)
__global__ void fill_sentinel(bf16* o, int n) {
  for (int i = blockIdx.x * blockDim.x + threadIdx.x; i < n; i += gridDim.x * blockDim.x)
    o[i] = __float2bfloat16(999.0f);
}

extern "C" void kernel_launch(void* const* d_in, const int* in_sizes, int n_in,
                              void* d_out, int out_size, void* d_ws, size_t ws_size,
                              hipStream_t stream) {
  const void* obs = d_in[0];
  const void* hs = d_in[1];
  const void* me_w1 = d_in[2];
  const void* me_b1 = d_in[3];
  const void* me_w2 = d_in[4];
  const void* me_b2 = d_in[5];
  const void* ae_w1 = d_in[6];
  const void* ae_b1 = d_in[7];
  const void* ae_w2 = d_in[8];
  const void* ae_b2 = d_in[9];
  const void* ipw = d_in[10];
  const void* ipb = d_in[11];
  const void* opw = d_in[12];
  const void* opb = d_in[13];
  const void* lng = d_in[14];
  const void* lnb = d_in[15];
  const void* wih = d_in[16];
  const void* whh = d_in[17];
  const void* bih = d_in[18];
  const void* bhh = d_in[19];
  const void* w0 = d_in[20];
  const void* b0 = d_in[21];
  const void* w1 = d_in[22];
  const void* b1 = d_in[23];
  const void* ow = d_in[24];
  const void* ob = d_in[25];

  const size_t xp_elems = (size_t)BB * SS * G3;    // 50,331,648
  const size_t go_elems = (size_t)BB * SS * HH;    // 16,777,216
  const size_t need = (xp_elems + go_elems) * sizeof(bf16);  // 128 MiB
  if (ws_size < need) {
    fill_sentinel<<<288, 256, 0, stream>>>((bf16*)d_out, out_size);
    return;
  }

  bf16* xp = (bf16*)d_ws;
  bf16* gout = xp + xp_elems;

  pre_kernel<<<(BB * SS) / 4, 256, 0, stream>>>(
      obs, me_w1, me_b1, me_w2, me_b2, ae_w1, ae_b1, ae_w2, ae_b2,
      ipw, ipb, opw, opb, lng, lnb, wih, bih, xp);

  gru_kernel<<<BB, G3, 0, stream>>>(obs, xp, hs, whh, bhh, gout, d_out);

  mlp_kernel<<<BB * SS, HH, 0, stream>>>(obs, gout, w0, b0, w1, b1, ow, ob, d_out);
}

// Round 5
// 3117.690 us; speedup vs baseline: 1.8204x; 1.8204x over previous
//
#include <hip/hip_runtime.h>
#include <hip/hip_bf16.h>

#define BB 128
#define SS 1024
#define HH 128
#define G3 384
#define NT (BB * SS)   // 131072 tokens

typedef __hip_bfloat16 bf16;
typedef unsigned int uint;

__device__ __forceinline__ float blo(uint u) { return __uint_as_float(u << 16); }
__device__ __forceinline__ float bhi(uint u) { return __uint_as_float(u & 0xffff0000u); }
__device__ __forceinline__ float leaky(float x) { return x >= 0.f ? x : 0.01f * x; }
// fp32 -> bf16 bits, round-to-nearest-even
__device__ __forceinline__ uint bf_rne(float f) {
  uint u = __float_as_uint(f);
  return (u + 0x7FFFu + ((u >> 16) & 1u)) >> 16;
}
// pack two consecutive global fp32 elements into one bf16-pair word
__device__ __forceinline__ uint pack2f(const float* p, int i) {
  return bf_rne(p[2 * i]) | (bf_rne(p[2 * i + 1]) << 16);
}

// dot of K fp32 (LDS) with K packed-bf16 weights (LDS uints, 16B-aligned rows)
template <int K>
__device__ __forceinline__ float dotl(const float* __restrict__ x,
                                      const uint* __restrict__ w, float acc) {
  const uint4* w4 = (const uint4*)w;
#pragma unroll
  for (int i = 0; i < K / 8; ++i) {
    uint4 uu = w4[i];
    acc += x[8 * i + 0] * blo(uu.x) + x[8 * i + 1] * bhi(uu.x) +
           x[8 * i + 2] * blo(uu.y) + x[8 * i + 3] * bhi(uu.y) +
           x[8 * i + 4] * blo(uu.z) + x[8 * i + 5] * bhi(uu.z) +
           x[8 * i + 6] * blo(uu.w) + x[8 * i + 7] * bhi(uu.w);
  }
  return acc;
}

// ---------------- pre_a: encoders + attention + LN -> xn fp32 [NT,64] -------
// s_small (floats): 0 me_w1[96] | 96 me_b1[32] | 128 me_b2[64] | 192 ae_w1[192]
// | 384 ae_b1[32] | 416 ae_b2[64] | 480 ipb[192] | 672 opb[64] | 736 lng[64]
// | 800 lnb[64]  (864 total)
__global__ __launch_bounds__(256) void pre_a(
    const float* __restrict__ obs, const float* __restrict__ me_w1,
    const float* __restrict__ me_b1, const float* __restrict__ me_w2,
    const float* __restrict__ me_b2, const float* __restrict__ ae_w1,
    const float* __restrict__ ae_b1, const float* __restrict__ ae_w2,
    const float* __restrict__ ae_b2, const float* __restrict__ ipw,
    const float* __restrict__ ipb, const float* __restrict__ opw,
    const float* __restrict__ opb, const float* __restrict__ lng,
    const float* __restrict__ lnb, float* __restrict__ xn_out) {
  __shared__ __align__(16) uint w_me2[1024];   // 2048 bf16
  __shared__ __align__(16) uint w_ae2[1024];
  __shared__ __align__(16) uint w_ip[6144];    // 12288 bf16
  __shared__ __align__(16) uint w_op[2048];
  __shared__ float s_small[864];
  __shared__ __align__(16) float scr[4 * 480];

  const int tid = threadIdx.x;
  for (int i = tid; i < 1024; i += 256) w_me2[i] = pack2f(me_w2, i);
  for (int i = tid; i < 1024; i += 256) w_ae2[i] = pack2f(ae_w2, i);
  for (int i = tid; i < 6144; i += 256) w_ip[i] = pack2f(ipw, i);
  for (int i = tid; i < 2048; i += 256) w_op[i] = pack2f(opw, i);
  if (tid < 96) s_small[tid] = me_w1[tid];
  if (tid < 32) s_small[96 + tid] = me_b1[tid];
  if (tid < 64) s_small[128 + tid] = me_b2[tid];
  if (tid < 192) s_small[192 + tid] = ae_w1[tid];
  if (tid < 32) s_small[384 + tid] = ae_b1[tid];
  if (tid < 64) s_small[416 + tid] = ae_b2[tid];
  if (tid < 192) s_small[480 + tid] = ipb[tid];
  if (tid < 64) s_small[672 + tid] = opb[tid];
  if (tid < 64) s_small[736 + tid] = lng[tid];
  if (tid < 64) s_small[800 + tid] = lnb[tid];
  __syncthreads();

  const int wid = tid >> 6, l = tid & 63;
  float* u = &scr[wid * 480];
  // scratch: 0..63 (enc1 m1/m2; later CTX) | 64..95 (enc1 ac) |
  // 96 M1E | 160 M2E | 224 ACE | 288 Q | 352 K1 | 416 K2

  for (int base = blockIdx.x * 4; base < NT; base += 4096) {
    const size_t token = base + wid;
    const size_t ob = token * 12;
    __syncthreads();  // WAR vs previous iteration's reads

    // stage 1: encoder hidden layers
    {
      const int half = l >> 5, row = l & 31;
      float i0 = obs[ob + 3 * half + 0];
      float i1 = obs[ob + 3 * half + 1];
      float i2 = obs[ob + 3 * half + 2];
      float acc = s_small[96 + row] + i0 * s_small[row * 3 + 0] +
                  i1 * s_small[row * 3 + 1] + i2 * s_small[row * 3 + 2];
      u[l] = leaky(acc);
      if (l < 32) {
        float a2 = s_small[384 + l];
#pragma unroll
        for (int j = 0; j < 6; ++j) a2 += obs[ob + 6 + j] * s_small[192 + l * 6 + j];
        u[64 + l] = leaky(a2);
      }
    }
    __syncthreads();

    // stage 2: encoder output layers
    float m1e = dotl<32>(u + 0, w_me2 + l * 16, s_small[128 + l]);
    float m2e = dotl<32>(u + 32, w_me2 + l * 16, s_small[128 + l]);
    float ace = dotl<32>(u + 64, w_ae2 + l * 16, s_small[416 + l]);
    u[96 + l] = m1e;
    u[160 + l] = m2e;
    u[224 + l] = ace;
    __syncthreads();

    // stage 3: q, k1, k2, v1, v2
    float q = dotl<64>(u + 224, w_ip + l * 32, s_small[480 + l]);
    float k1 = dotl<64>(u + 96, w_ip + (64 + l) * 32, s_small[480 + 64 + l]);
    float k2 = dotl<64>(u + 160, w_ip + (64 + l) * 32, s_small[480 + 64 + l]);
    float v1 = dotl<64>(u + 96, w_ip + (128 + l) * 32, s_small[480 + 128 + l]);
    float v2 = dotl<64>(u + 160, w_ip + (128 + l) * 32, s_small[480 + 128 + l]);
    u[288 + l] = q;
    u[352 + l] = k1;
    u[416 + l] = k2;
    __syncthreads();

    // stage 4: 2-key attention per head (HD=16)
    {
      const int hd = l >> 4;
      float s1 = 0.f, s2 = 0.f;
#pragma unroll
      for (int d = 0; d < 16; ++d) {
        float qq = u[288 + hd * 16 + d];
        s1 += qq * u[352 + hd * 16 + d];
        s2 += qq * u[416 + hd * 16 + d];
      }
      s1 *= 0.25f;
      s2 *= 0.25f;
      float mx = fmaxf(s1, s2);
      float e1 = __expf(s1 - mx), e2 = __expf(s2 - mx);
      float a1 = e1 / (e1 + e2);
      u[l] = a1 * v1 + (1.f - a1) * v2;  // CTX
    }
    __syncthreads();

    // out_proj + residual + LayerNorm -> xn (fp32)
    float ao = dotl<64>(u + 0, w_op + l * 32, s_small[672 + l]);
    float x = ao + ace;
    float s = x, s2s = x * x;
#pragma unroll
    for (int off = 32; off; off >>= 1) {
      s += __shfl_xor(s, off);
      s2s += __shfl_xor(s2s, off);
    }
    float mu = s * (1.f / 64.f);
    float var = s2s * (1.f / 64.f) - mu * mu;
    float rs = rsqrtf(var + 1e-5f);
    xn_out[token * 64 + l] = (x - mu) * rs * s_small[736 + l] + s_small[800 + l];
  }
}

// ---------------- pre_b: xp = xn @ W_ih.T + b_ih  (bf16 out) ----------------
__global__ __launch_bounds__(256) void pre_b(const float* __restrict__ xn_in,
                                             const float* __restrict__ wih,
                                             const float* __restrict__ bih,
                                             bf16* __restrict__ xp) {
  __shared__ __align__(16) uint w[12288];  // 24576 bf16 = 48 KB
  __shared__ float sb[G3];
  __shared__ __align__(16) float xs[4 * 64];
  const int tid = threadIdx.x;
  for (int i = tid; i < 12288; i += 256) w[i] = pack2f(wih, i);
  for (int i = tid; i < G3; i += 256) sb[i] = bih[i];
  __syncthreads();

  const int wid = tid >> 6, l = tid & 63;
  float* x = &xs[wid * 64];
  for (int base = blockIdx.x * 4; base < NT; base += 4096) {
    const size_t token = base + wid;
    __syncthreads();
    x[l] = xn_in[token * 64 + l];
    __syncthreads();
    const size_t outb = token * G3;
#pragma unroll
    for (int r = 0; r < 6; ++r) {
      const int j = r * 64 + l;
      float a = dotl<64>(x, w + j * 32, sb[j]);
      xp[outb + j] = __float2bfloat16(a);
    }
  }
}

// ---------------- gru: sequential, one block per chain ----------------------
__global__ __launch_bounds__(384) void gru_kernel(const bf16* __restrict__ xp,
                                                  const float* __restrict__ hs,
                                                  const float* __restrict__ whh,
                                                  const float* __restrict__ bhh,
                                                  bf16* __restrict__ gout,
                                                  float* __restrict__ hlast) {
  __shared__ __align__(16) float hl[HH];
  __shared__ float hp[G3];
  __shared__ float xq[G3];
  const int j = threadIdx.x;
  const int b = blockIdx.x;

  // thread j holds W_hh row j as 128 fp32 in registers
  float w[128];
  {
    const float* wr = whh + (size_t)j * HH;
#pragma unroll
    for (int i = 0; i < 128; ++i) w[i] = wr[i];
  }
  const float bias = bhh[j];
  if (j < HH) hl[j] = hs[b * HH + j];
  __syncthreads();

  const bf16* xrow = xp + (size_t)b * SS * G3 + j;
  bf16* grow = gout + (size_t)b * SS * HH;
  float xnext = __bfloat162float(xrow[0]);

  for (int t = 0; t < SS; ++t) {
    float xv = xnext;
    if (t + 1 < SS) xnext = __bfloat162float(xrow[(size_t)(t + 1) * G3]);  // prefetch
    float acc = bias;
    const float4* h4 = (const float4*)hl;
#pragma unroll
    for (int i = 0; i < 32; ++i) {
      float4 hv = h4[i];
      acc += hv.x * w[4 * i] + hv.y * w[4 * i + 1] + hv.z * w[4 * i + 2] +
             hv.w * w[4 * i + 3];
    }
    hp[j] = acc;
    xq[j] = xv;
    __syncthreads();
    if (j < HH) {
      float r = 1.f / (1.f + __expf(-(xq[j] + hp[j])));
      float z = 1.f / (1.f + __expf(-(xq[HH + j] + hp[HH + j])));
      float gp = xq[2 * HH + j] + r * hp[2 * HH + j];
      float e = __expf(-2.f * fabsf(gp));
      float th = copysignf((1.f - e) / (1.f + e), gp);
      float hn = (1.f - z) * th + z * hl[j];
      hl[j] = hn;
      grow[(size_t)t * HH + j] = __float2bfloat16(hn);
    }
    __syncthreads();
  }
  if (j < HH) hlast[b * HH + j] = hl[j];
}

// ---------------- mlp0: f0 = leaky(g @ w0.T + b0)  (fp32 out) ---------------
__global__ __launch_bounds__(256) void mlp0(const bf16* __restrict__ gin,
                                            const float* __restrict__ w0b,
                                            const float* __restrict__ b0b,
                                            float* __restrict__ f0) {
  __shared__ __align__(16) uint w[8192];  // 16384 bf16 = 32 KB
  __shared__ float bb[HH];
  __shared__ __align__(16) float gs[4 * HH];
  const int tid = threadIdx.x;
  for (int i = tid; i < 8192; i += 256) w[i] = pack2f(w0b, i);
  if (tid < HH) bb[tid] = b0b[tid];
  __syncthreads();

  const int wid = tid >> 6, l = tid & 63;
  float* g = &gs[wid * HH];
  for (int base = blockIdx.x * 4; base < NT; base += 4096) {
    const size_t token = base + wid;
    __syncthreads();
    {
      // gin lives in d_ws (we control alignment): dword read is safe
      uint uu = ((const uint*)(gin + token * HH))[l];
      g[2 * l] = blo(uu);
      g[2 * l + 1] = bhi(uu);
    }
    __syncthreads();
    float A = bb[l], B = bb[64 + l];
    const uint4* wa = (const uint4*)(w + l * 64);
    const uint4* wb = (const uint4*)(w + (64 + l) * 64);
#pragma unroll
    for (int i = 0; i < 16; ++i) {
      uint4 ua = wa[i], ub = wb[i];
      float x0 = g[8 * i + 0], x1 = g[8 * i + 1], x2 = g[8 * i + 2], x3 = g[8 * i + 3];
      float x4 = g[8 * i + 4], x5 = g[8 * i + 5], x6 = g[8 * i + 6], x7 = g[8 * i + 7];
      A += x0 * blo(ua.x) + x1 * bhi(ua.x) + x2 * blo(ua.y) + x3 * bhi(ua.y) +
           x4 * blo(ua.z) + x5 * bhi(ua.z) + x6 * blo(ua.w) + x7 * bhi(ua.w);
      B += x0 * blo(ub.x) + x1 * bhi(ub.x) + x2 * blo(ub.y) + x3 * bhi(ub.y) +
           x4 * blo(ub.z) + x5 * bhi(ub.z) + x6 * blo(ub.w) + x7 * bhi(ub.w);
    }
    f0[token * HH + l] = leaky(A);
    f0[token * HH + 64 + l] = leaky(B);
  }
}

// ---------------- mlp1: f1 = leaky(f0 @ w1.T + b1); value = f1 @ ow.T + ob --
__global__ __launch_bounds__(256) void mlp1(const float* __restrict__ f0,
                                            const float* __restrict__ w1b,
                                            const float* __restrict__ b1b,
                                            const float* __restrict__ ow,
                                            const float* __restrict__ obp,
                                            float* __restrict__ value) {
  __shared__ __align__(16) uint w[8192];
  __shared__ float bb[HH];
  __shared__ float ows[HH];
  __shared__ __align__(16) float gs[4 * HH];
  const int tid = threadIdx.x;
  for (int i = tid; i < 8192; i += 256) w[i] = pack2f(w1b, i);
  if (tid < HH) bb[tid] = b1b[tid];
  if (tid < HH) ows[tid] = ow[tid];
  __syncthreads();
  const float obias = obp[0];

  const int wid = tid >> 6, l = tid & 63;
  float* g = &gs[wid * HH];
  for (int base = blockIdx.x * 4; base < NT; base += 4096) {
    const size_t token = base + wid;
    __syncthreads();
    {
      float2 v = ((const float2*)(f0 + token * HH))[l];  // d_ws: aligned
      g[2 * l] = v.x;
      g[2 * l + 1] = v.y;
    }
    __syncthreads();
    float A = bb[l], B = bb[64 + l];
    const uint4* wa = (const uint4*)(w + l * 64);
    const uint4* wb = (const uint4*)(w + (64 + l) * 64);
#pragma unroll
    for (int i = 0; i < 16; ++i) {
      uint4 ua = wa[i], ub = wb[i];
      float x0 = g[8 * i + 0], x1 = g[8 * i + 1], x2 = g[8 * i + 2], x3 = g[8 * i + 3];
      float x4 = g[8 * i + 4], x5 = g[8 * i + 5], x6 = g[8 * i + 6], x7 = g[8 * i + 7];
      A += x0 * blo(ua.x) + x1 * bhi(ua.x) + x2 * blo(ua.y) + x3 * bhi(ua.y) +
           x4 * blo(ua.z) + x5 * bhi(ua.z) + x6 * blo(ua.w) + x7 * bhi(ua.w);
      B += x0 * blo(ub.x) + x1 * bhi(ub.x) + x2 * blo(ub.y) + x3 * bhi(ub.y) +
           x4 * blo(ub.z) + x5 * bhi(ub.z) + x6 * blo(ub.w) + x7 * bhi(ub.w);
    }
    float p = leaky(A) * ows[l] + leaky(B) * ows[64 + l];
#pragma unroll
    for (int off = 32; off; off >>= 1) p += __shfl_xor(p, off);
    if (l == 0) value[token] = p + obias;
  }
}

__global__ void fill_sentinel(float* o, int n) {
  for (int i = blockIdx.x * blockDim.x + threadIdx.x; i < n; i += gridDim.x * blockDim.x)
    o[i] = 999.0f;
}

extern "C" void kernel_launch(void* const* d_in, const int* in_sizes, int n_in,
                              void* d_out, int out_size, void* d_ws, size_t ws_size,
                              hipStream_t stream) {
  const float* obs = (const float*)d_in[0];
  const float* hs = (const float*)d_in[1];
  const float* me_w1 = (const float*)d_in[2];
  const float* me_b1 = (const float*)d_in[3];
  const float* me_w2 = (const float*)d_in[4];
  const float* me_b2 = (const float*)d_in[5];
  const float* ae_w1 = (const float*)d_in[6];
  const float* ae_b1 = (const float*)d_in[7];
  const float* ae_w2 = (const float*)d_in[8];
  const float* ae_b2 = (const float*)d_in[9];
  const float* ipw = (const float*)d_in[10];
  const float* ipb = (const float*)d_in[11];
  const float* opw = (const float*)d_in[12];
  const float* opb = (const float*)d_in[13];
  const float* lng = (const float*)d_in[14];
  const float* lnb = (const float*)d_in[15];
  const float* wih = (const float*)d_in[16];
  const float* whh = (const float*)d_in[17];
  const float* bih = (const float*)d_in[18];
  const float* bhh = (const float*)d_in[19];
  const float* w0 = (const float*)d_in[20];
  const float* b0 = (const float*)d_in[21];
  const float* w1 = (const float*)d_in[22];
  const float* b1 = (const float*)d_in[23];
  const float* ow = (const float*)d_in[24];
  const float* ob = (const float*)d_in[25];

  // workspace layout (need = 128 MiB):
  //  region A [0, 100.66MB): xp bf16 [NT,384]; after gru reuses as f0 fp32 [NT,128]
  //  region B [100.66MB, 134.22MB): xn fp32 [NT,64]; after pre_b reuses as gout bf16 [NT,128]
  const size_t regA_bytes = (size_t)NT * G3 * sizeof(bf16);   // 100,663,296
  const size_t regB_bytes = (size_t)NT * 64 * sizeof(float);  // 33,554,432 (== NT*128*2)
  const size_t need = regA_bytes + regB_bytes;                // 134,217,728
  float* out = (float*)d_out;
  if (ws_size < need) {
    fill_sentinel<<<288, 256, 0, stream>>>(out, out_size);
    return;
  }

  char* ws = (char*)d_ws;
  bf16* xp = (bf16*)ws;
  float* f0 = (float*)ws;
  float* xnf = (float*)(ws + regA_bytes);
  bf16* gout = (bf16*)(ws + regA_bytes);

  pre_a<<<1024, 256, 0, stream>>>(obs, me_w1, me_b1, me_w2, me_b2, ae_w1, ae_b1,
                                  ae_w2, ae_b2, ipw, ipb, opw, opb, lng, lnb, xnf);
  pre_b<<<1024, 256, 0, stream>>>(xnf, wih, bih, xp);
  gru_kernel<<<BB, G3, 0, stream>>>(xp, hs, whh, bhh, gout, out + NT);
  mlp0<<<1024, 256, 0, stream>>>(gout, w0, b0, f0);
  mlp1<<<1024, 256, 0, stream>>>(f0, w1, b1, ow, ob, out);
}

// Round 6
// 2789.329 us; speedup vs baseline: 2.0347x; 1.1177x over previous
//
#include <hip/hip_runtime.h>
#include <hip/hip_bf16.h>

#define BB 128
#define SS 1024
#define HH 128
#define G3 384
#define NT (BB * SS)   // 131072 tokens

typedef __hip_bfloat16 bf16;
typedef unsigned int uint;
typedef _Float16 f16;
typedef f16 f16x2 __attribute__((ext_vector_type(2)));

__device__ __forceinline__ float blo(uint u) { return __uint_as_float(u << 16); }
__device__ __forceinline__ float bhi(uint u) { return __uint_as_float(u & 0xffff0000u); }
__device__ __forceinline__ float leaky(float x) { return x >= 0.f ? x : 0.01f * x; }
// fp32 -> bf16 bits, round-to-nearest-even
__device__ __forceinline__ uint bf_rne(float f) {
  uint u = __float_as_uint(f);
  return (u + 0x7FFFu + ((u >> 16) & 1u)) >> 16;
}
__device__ __forceinline__ uint pack2f(const float* p, int i) {
  return bf_rne(p[2 * i]) | (bf_rne(p[2 * i + 1]) << 16);
}

// load K floats from LDS into registers via float4 (ptr must be 16B aligned)
template <int K>
__device__ __forceinline__ void ldx(const float* __restrict__ x, float* __restrict__ r) {
#pragma unroll
  for (int i = 0; i < K / 4; ++i) {
    float4 v = ((const float4*)x)[i];
    r[4 * i + 0] = v.x; r[4 * i + 1] = v.y; r[4 * i + 2] = v.z; r[4 * i + 3] = v.w;
  }
}
// dot: x in registers, w packed-bf16 uints in LDS (16B-aligned rows)
template <int K>
__device__ __forceinline__ float dotr(const float* __restrict__ xr,
                                      const uint* __restrict__ w, float acc) {
  const uint4* w4 = (const uint4*)w;
#pragma unroll
  for (int i = 0; i < K / 8; ++i) {
    uint4 uu = w4[i];
    acc += xr[8 * i + 0] * blo(uu.x) + xr[8 * i + 1] * bhi(uu.x) +
           xr[8 * i + 2] * blo(uu.y) + xr[8 * i + 3] * bhi(uu.y) +
           xr[8 * i + 4] * blo(uu.z) + xr[8 * i + 5] * bhi(uu.z) +
           xr[8 * i + 6] * blo(uu.w) + xr[8 * i + 7] * bhi(uu.w);
  }
  return acc;
}

// ---------------- pre_a: encoders + attention + LN -> xn fp32 [NT,64] -------
__global__ __launch_bounds__(256) void pre_a(
    const float* __restrict__ obs, const float* __restrict__ me_w1,
    const float* __restrict__ me_b1, const float* __restrict__ me_w2,
    const float* __restrict__ me_b2, const float* __restrict__ ae_w1,
    const float* __restrict__ ae_b1, const float* __restrict__ ae_w2,
    const float* __restrict__ ae_b2, const float* __restrict__ ipw,
    const float* __restrict__ ipb, const float* __restrict__ opw,
    const float* __restrict__ opb, const float* __restrict__ lng,
    const float* __restrict__ lnb, float* __restrict__ xn_out) {
  __shared__ __align__(16) uint w_me2[1024];
  __shared__ __align__(16) uint w_ae2[1024];
  __shared__ __align__(16) uint w_ip[6144];
  __shared__ __align__(16) uint w_op[2048];
  __shared__ float s_small[864];
  __shared__ __align__(16) float scr[4 * 480];

  const int tid = threadIdx.x;
  for (int i = tid; i < 1024; i += 256) w_me2[i] = pack2f(me_w2, i);
  for (int i = tid; i < 1024; i += 256) w_ae2[i] = pack2f(ae_w2, i);
  for (int i = tid; i < 6144; i += 256) w_ip[i] = pack2f(ipw, i);
  for (int i = tid; i < 2048; i += 256) w_op[i] = pack2f(opw, i);
  if (tid < 96) s_small[tid] = me_w1[tid];
  if (tid < 32) s_small[96 + tid] = me_b1[tid];
  if (tid < 64) s_small[128 + tid] = me_b2[tid];
  if (tid < 192) s_small[192 + tid] = ae_w1[tid];
  if (tid < 32) s_small[384 + tid] = ae_b1[tid];
  if (tid < 64) s_small[416 + tid] = ae_b2[tid];
  if (tid < 192) s_small[480 + tid] = ipb[tid];
  if (tid < 64) s_small[672 + tid] = opb[tid];
  if (tid < 64) s_small[736 + tid] = lng[tid];
  if (tid < 64) s_small[800 + tid] = lnb[tid];
  __syncthreads();

  const int wid = tid >> 6, l = tid & 63;
  float* u = &scr[wid * 480];
  // 0..63 enc1-m1/m2 (later CTX) | 64..95 enc1-ac | 96 M1E | 160 M2E | 224 ACE
  // | 288 Q | 352 K1 | 416 K2
  float xr[64];

  for (int base = blockIdx.x * 4; base < NT; base += 4096) {
    const size_t token = base + wid;
    const size_t ob = token * 12;
    __syncthreads();  // WAR vs previous iteration

    {  // stage 1: encoder hidden layers
      const int half = l >> 5, row = l & 31;
      float i0 = obs[ob + 3 * half + 0];
      float i1 = obs[ob + 3 * half + 1];
      float i2 = obs[ob + 3 * half + 2];
      float acc = s_small[96 + row] + i0 * s_small[row * 3 + 0] +
                  i1 * s_small[row * 3 + 1] + i2 * s_small[row * 3 + 2];
      u[l] = leaky(acc);
      if (l < 32) {
        float a2 = s_small[384 + l];
#pragma unroll
        for (int j = 0; j < 6; ++j) a2 += obs[ob + 6 + j] * s_small[192 + l * 6 + j];
        u[64 + l] = leaky(a2);
      }
    }
    __syncthreads();

    // stage 2: encoder output layers (x staged to registers, b128 LDS reads)
    ldx<32>(u + 0, xr);
    float m1e = dotr<32>(xr, w_me2 + l * 16, s_small[128 + l]);
    ldx<32>(u + 32, xr);
    float m2e = dotr<32>(xr, w_me2 + l * 16, s_small[128 + l]);
    ldx<32>(u + 64, xr);
    float ace = dotr<32>(xr, w_ae2 + l * 16, s_small[416 + l]);
    u[96 + l] = m1e;
    u[160 + l] = m2e;
    u[224 + l] = ace;
    __syncthreads();

    // stage 3: q,k1,k2,v1,v2 with x-register reuse
    ldx<64>(u + 96, xr);
    float k1 = dotr<64>(xr, w_ip + (64 + l) * 32, s_small[480 + 64 + l]);
    float v1 = dotr<64>(xr, w_ip + (128 + l) * 32, s_small[480 + 128 + l]);
    ldx<64>(u + 160, xr);
    float k2 = dotr<64>(xr, w_ip + (64 + l) * 32, s_small[480 + 64 + l]);
    float v2 = dotr<64>(xr, w_ip + (128 + l) * 32, s_small[480 + 128 + l]);
    ldx<64>(u + 224, xr);
    float q = dotr<64>(xr, w_ip + l * 32, s_small[480 + l]);
    u[288 + l] = q;
    u[352 + l] = k1;
    u[416 + l] = k2;
    __syncthreads();

    {  // stage 4: 2-key attention per head (HD=16)
      const int hd = l >> 4;
      float s1 = 0.f, s2 = 0.f;
#pragma unroll
      for (int d = 0; d < 16; ++d) {
        float qq = u[288 + hd * 16 + d];
        s1 += qq * u[352 + hd * 16 + d];
        s2 += qq * u[416 + hd * 16 + d];
      }
      s1 *= 0.25f;
      s2 *= 0.25f;
      float mx = fmaxf(s1, s2);
      float e1 = __expf(s1 - mx), e2 = __expf(s2 - mx);
      float a1 = e1 / (e1 + e2);
      u[l] = a1 * v1 + (1.f - a1) * v2;  // CTX
    }
    __syncthreads();

    // out_proj + residual + LayerNorm -> xn (fp32)
    ldx<64>(u + 0, xr);
    float ao = dotr<64>(xr, w_op + l * 32, s_small[672 + l]);
    float x = ao + ace;
    float s = x, s2s = x * x;
#pragma unroll
    for (int off = 32; off; off >>= 1) {
      s += __shfl_xor(s, off);
      s2s += __shfl_xor(s2s, off);
    }
    float mu = s * (1.f / 64.f);
    float var = s2s * (1.f / 64.f) - mu * mu;
    float rs = rsqrtf(var + 1e-5f);
    xn_out[token * 64 + l] = (x - mu) * rs * s_small[736 + l] + s_small[800 + l];
  }
}

// ---------------- pre_b: xp = xn @ W_ih.T + b_ih  (bf16 out) ----------------
__global__ __launch_bounds__(256) void pre_b(const float* __restrict__ xn_in,
                                             const float* __restrict__ wih,
                                             const float* __restrict__ bih,
                                             bf16* __restrict__ xp) {
  __shared__ __align__(16) uint w[12288];  // 384 rows x 32 uints
  __shared__ float sb[G3];
  __shared__ __align__(16) float xs[4 * 64];
  const int tid = threadIdx.x;
  for (int i = tid; i < 12288; i += 256) w[i] = pack2f(wih, i);
  for (int i = tid; i < G3; i += 256) sb[i] = bih[i];
  __syncthreads();

  const int wid = tid >> 6, l = tid & 63;
  float* x = &xs[wid * 64];
  float xr[64];
  for (int base = blockIdx.x * 4; base < NT; base += 4096) {
    const size_t token = base + wid;
    __syncthreads();
    x[l] = xn_in[token * 64 + l];
    __syncthreads();
    ldx<64>(x, xr);
    const size_t outb = token * G3;
#pragma unroll
    for (int r = 0; r < 6; ++r) {
      const int j = r * 64 + l;
      xp[outb + j] = __float2bfloat16(dotr<64>(xr, w + j * 32, sb[j]));
    }
  }
}

// ---------------- gru: readlane + v_dot2_f32_f16, zero-LDS dot --------------
__global__ __launch_bounds__(384) void gru_kernel(const bf16* __restrict__ xp,
                                                  const float* __restrict__ hs,
                                                  const float* __restrict__ whh,
                                                  const float* __restrict__ bhh,
                                                  bf16* __restrict__ gout,
                                                  float* __restrict__ hlast) {
  __shared__ __align__(4) unsigned short hsk[HH];  // h as f16 bits
  __shared__ float hp[G3];
  __shared__ float xq[G3];
  const int j = threadIdx.x;
  const int b = blockIdx.x;
  const int lane = j & 63;

  // thread j holds W_hh row j as 64 packed f16 pairs in registers
  f16x2 wpk[64];
  {
    const float* wr = whh + (size_t)j * HH;
#pragma unroll
    for (int i = 0; i < 64; ++i) {
      f16x2 v;
      v.x = (f16)wr[2 * i];
      v.y = (f16)wr[2 * i + 1];
      wpk[i] = v;
    }
  }
  const float bias = bhh[j];
  float hprev = 0.f;
  if (j < HH) {
    hprev = hs[b * HH + j];
    hsk[j] = __builtin_bit_cast(unsigned short, (f16)hprev);
  }
  __syncthreads();

  const bf16* xrow = xp + (size_t)b * SS * G3 + j;
  bf16* grow = gout + (size_t)b * SS * HH;
  float xnext = __bfloat162float(xrow[0]);

  for (int t = 0; t < SS; ++t) {
    float xv = xnext;
    if (t + 1 < SS) xnext = __bfloat162float(xrow[(size_t)(t + 1) * G3]);
    // each lane reads one packed f16 h-pair; full h broadcast via readlane
    uint hw = ((const uint*)hsk)[lane];
    float a0 = 0.f, a1 = 0.f;
#pragma unroll
    for (int i = 0; i < 64; i += 2) {
      uint s0 = (uint)__builtin_amdgcn_readlane((int)hw, i);
      uint s1 = (uint)__builtin_amdgcn_readlane((int)hw, i + 1);
      a0 = __builtin_amdgcn_fdot2(__builtin_bit_cast(f16x2, s0), wpk[i], a0, false);
      a1 = __builtin_amdgcn_fdot2(__builtin_bit_cast(f16x2, s1), wpk[i + 1], a1, false);
    }
    hp[j] = bias + a0 + a1;
    xq[j] = xv;
    __syncthreads();
    if (j < HH) {
      float r = 1.f / (1.f + __expf(-(xq[j] + hp[j])));
      float z = 1.f / (1.f + __expf(-(xq[HH + j] + hp[HH + j])));
      float gp = xq[2 * HH + j] + r * hp[2 * HH + j];
      float e = __expf(-2.f * fabsf(gp));
      float th = copysignf((1.f - e) / (1.f + e), gp);
      float hn = (1.f - z) * th + z * hprev;
      hprev = hn;
      hsk[j] = __builtin_bit_cast(unsigned short, (f16)hn);
      grow[(size_t)t * HH + j] = __float2bfloat16(hn);
    }
    __syncthreads();
  }
  if (j < HH) hlast[b * HH + j] = hprev;
}

// ---------------- mlp0: f0 = leaky(g @ w0.T + b0)  (bf16 out) ---------------
__global__ __launch_bounds__(256) void mlp0(const bf16* __restrict__ gin,
                                            const float* __restrict__ w0b,
                                            const float* __restrict__ b0b,
                                            bf16* __restrict__ f0) {
  __shared__ __align__(16) uint w[8192];  // 128 rows x 64 uints
  __shared__ float bb[HH];
  __shared__ __align__(16) float gs[4 * HH];
  const int tid = threadIdx.x;
  for (int i = tid; i < 8192; i += 256) w[i] = pack2f(w0b, i);
  if (tid < HH) bb[tid] = b0b[tid];
  __syncthreads();

  const int wid = tid >> 6, l = tid & 63;
  float* g = &gs[wid * HH];
  for (int base = blockIdx.x * 4; base < NT; base += 4096) {
    const size_t token = base + wid;
    __syncthreads();
    {
      uint uu = ((const uint*)(gin + token * HH))[l];  // d_ws: aligned
      g[2 * l] = blo(uu);
      g[2 * l + 1] = bhi(uu);
    }
    __syncthreads();
    float A = bb[l], B = bb[64 + l];
#pragma unroll
    for (int c = 0; c < 4; ++c) {
      float xr[32];
      ldx<32>(g + 32 * c, xr);
      A = dotr<32>(xr, w + l * 64 + c * 16, A);
      B = dotr<32>(xr, w + (64 + l) * 64 + c * 16, B);
    }
    f0[token * HH + l] = __float2bfloat16(leaky(A));
    f0[token * HH + 64 + l] = __float2bfloat16(leaky(B));
  }
}

// ---------------- mlp1: value = leaky(f0@w1.T+b1) @ ow.T + ob ---------------
__global__ __launch_bounds__(256) void mlp1(const bf16* __restrict__ f0,
                                            const float* __restrict__ w1b,
                                            const float* __restrict__ b1b,
                                            const float* __restrict__ ow,
                                            const float* __restrict__ obp,
                                            float* __restrict__ value) {
  __shared__ __align__(16) uint w[8192];
  __shared__ float bb[HH];
  __shared__ float ows[HH];
  __shared__ __align__(16) float gs[4 * HH];
  const int tid = threadIdx.x;
  for (int i = tid; i < 8192; i += 256) w[i] = pack2f(w1b, i);
  if (tid < HH) bb[tid] = b1b[tid];
  if (tid < HH) ows[tid] = ow[tid];
  __syncthreads();
  const float obias = obp[0];

  const int wid = tid >> 6, l = tid & 63;
  float* g = &gs[wid * HH];
  for (int base = blockIdx.x * 4; base < NT; base += 4096) {
    const size_t token = base + wid;
    __syncthreads();
    {
      uint uu = ((const uint*)(f0 + token * HH))[l];  // d_ws: aligned
      g[2 * l] = blo(uu);
      g[2 * l + 1] = bhi(uu);
    }
    __syncthreads();
    float A = bb[l], B = bb[64 + l];
#pragma unroll
    for (int c = 0; c < 4; ++c) {
      float xr[32];
      ldx<32>(g + 32 * c, xr);
      A = dotr<32>(xr, w + l * 64 + c * 16, A);
      B = dotr<32>(xr, w + (64 + l) * 64 + c * 16, B);
    }
    float p = leaky(A) * ows[l] + leaky(B) * ows[64 + l];
#pragma unroll
    for (int off = 32; off; off >>= 1) p += __shfl_xor(p, off);
    if (l == 0) value[token] = p + obias;
  }
}

__global__ void fill_sentinel(float* o, int n) {
  for (int i = blockIdx.x * blockDim.x + threadIdx.x; i < n; i += gridDim.x * blockDim.x)
    o[i] = 999.0f;
}

extern "C" void kernel_launch(void* const* d_in, const int* in_sizes, int n_in,
                              void* d_out, int out_size, void* d_ws, size_t ws_size,
                              hipStream_t stream) {
  const float* obs = (const float*)d_in[0];
  const float* hs = (const float*)d_in[1];
  const float* me_w1 = (const float*)d_in[2];
  const float* me_b1 = (const float*)d_in[3];
  const float* me_w2 = (const float*)d_in[4];
  const float* me_b2 = (const float*)d_in[5];
  const float* ae_w1 = (const float*)d_in[6];
  const float* ae_b1 = (const float*)d_in[7];
  const float* ae_w2 = (const float*)d_in[8];
  const float* ae_b2 = (const float*)d_in[9];
  const float* ipw = (const float*)d_in[10];
  const float* ipb = (const float*)d_in[11];
  const float* opw = (const float*)d_in[12];
  const float* opb = (const float*)d_in[13];
  const float* lng = (const float*)d_in[14];
  const float* lnb = (const float*)d_in[15];
  const float* wih = (const float*)d_in[16];
  const float* whh = (const float*)d_in[17];
  const float* bih = (const float*)d_in[18];
  const float* bhh = (const float*)d_in[19];
  const float* w0 = (const float*)d_in[20];
  const float* b0 = (const float*)d_in[21];
  const float* w1 = (const float*)d_in[22];
  const float* b1 = (const float*)d_in[23];
  const float* ow = (const float*)d_in[24];
  const float* ob = (const float*)d_in[25];

  // workspace (128 MiB):
  //  region A [0, 100.66MB): xp bf16 [NT,384]; later f0 bf16 [NT,128]
  //  region B [100.66MB, 134.22MB): xn fp32 [NT,64]; later gout bf16 [NT,128]
  const size_t regA_bytes = (size_t)NT * G3 * sizeof(bf16);
  const size_t regB_bytes = (size_t)NT * 64 * sizeof(float);
  const size_t need = regA_bytes + regB_bytes;  // 134,217,728
  float* out = (float*)d_out;
  if (ws_size < need) {
    fill_sentinel<<<288, 256, 0, stream>>>(out, out_size);
    return;
  }

  char* ws = (char*)d_ws;
  bf16* xp = (bf16*)ws;
  bf16* f0 = (bf16*)ws;
  float* xnf = (float*)(ws + regA_bytes);
  bf16* gout = (bf16*)(ws + regA_bytes);

  pre_a<<<1024, 256, 0, stream>>>(obs, me_w1, me_b1, me_w2, me_b2, ae_w1, ae_b1,
                                  ae_w2, ae_b2, ipw, ipb, opw, opb, lng, lnb, xnf);
  pre_b<<<1024, 256, 0, stream>>>(xnf, wih, bih, xp);
  gru_kernel<<<BB, G3, 0, stream>>>(xp, hs, whh, bhh, gout, out + NT);
  mlp0<<<1024, 256, 0, stream>>>(gout, w0, b0, f0);
  mlp1<<<1024, 256, 0, stream>>>(f0, w1, b1, ow, ob, out);
}

// Round 7
// 1647.546 us; speedup vs baseline: 3.4447x; 1.6930x over previous
//
#include <hip/hip_runtime.h>
#include <hip/hip_bf16.h>

#define BB 128
#define SS 1024
#define HH 128
#define G3 384
#define NT (BB * SS)   // 131072 tokens

typedef __hip_bfloat16 bf16;
typedef unsigned int uint;
typedef _Float16 f16;
typedef f16 f16x2 __attribute__((ext_vector_type(2)));

__device__ __forceinline__ float blo(uint u) { return __uint_as_float(u << 16); }
__device__ __forceinline__ float bhi(uint u) { return __uint_as_float(u & 0xffff0000u); }
__device__ __forceinline__ float leaky(float x) { return x >= 0.f ? x : 0.01f * x; }
__device__ __forceinline__ uint bf_rne(float f) {
  uint u = __float_as_uint(f);
  return (u + 0x7FFFu + ((u >> 16) & 1u)) >> 16;
}
__device__ __forceinline__ uint pack2f(const float* p, int i) {
  return bf_rne(p[2 * i]) | (bf_rne(p[2 * i + 1]) << 16);
}
__device__ __forceinline__ f16x2 u2h(uint u) { return __builtin_bit_cast(f16x2, u); }

// LDS-LDS dot with XOR-rotated chunk order: lane-dependent chunk start spreads
// the wave's ds_read_b128 windows across all banks (power-of-2 row stride would
// put all 64 lanes in one 4-bank window -> ~64-way conflict).
template <int K>
__device__ __forceinline__ float dot_rot(const float* __restrict__ xl,
                                         const uint* __restrict__ wrow,
                                         int lane, float acc) {
  constexpr int n = K / 8;
  const uint4* w4 = (const uint4*)wrow;
  const float4* x4 = (const float4*)xl;
  const int c0 = lane & (n - 1);
#pragma unroll
  for (int ci = 0; ci < n; ++ci) {
    const int c = c0 ^ ci;
    uint4 uu = w4[c];
    float4 a = x4[2 * c], b = x4[2 * c + 1];
    acc += a.x * blo(uu.x) + a.y * bhi(uu.x) + a.z * blo(uu.y) + a.w * bhi(uu.y) +
           b.x * blo(uu.z) + b.y * bhi(uu.z) + b.z * blo(uu.w) + b.w * bhi(uu.w);
  }
  return acc;
}

// ---------------- pre_a: encoders + attention + LN -> xn fp32 [NT,64] -------
__global__ __launch_bounds__(256) void pre_a(
    const float* __restrict__ obs, const float* __restrict__ me_w1,
    const float* __restrict__ me_b1, const float* __restrict__ me_w2,
    const float* __restrict__ me_b2, const float* __restrict__ ae_w1,
    const float* __restrict__ ae_b1, const float* __restrict__ ae_w2,
    const float* __restrict__ ae_b2, const float* __restrict__ ipw,
    const float* __restrict__ ipb, const float* __restrict__ opw,
    const float* __restrict__ opb, const float* __restrict__ lng,
    const float* __restrict__ lnb, float* __restrict__ xn_out) {
  __shared__ __align__(16) uint w_me2[1024];
  __shared__ __align__(16) uint w_ae2[1024];
  __shared__ __align__(16) uint w_ip[6144];
  __shared__ __align__(16) uint w_op[2048];
  __shared__ float s_small[864];
  __shared__ __align__(16) float scr[4 * 480];

  const int tid = threadIdx.x;
  for (int i = tid; i < 1024; i += 256) w_me2[i] = pack2f(me_w2, i);
  for (int i = tid; i < 1024; i += 256) w_ae2[i] = pack2f(ae_w2, i);
  for (int i = tid; i < 6144; i += 256) w_ip[i] = pack2f(ipw, i);
  for (int i = tid; i < 2048; i += 256) w_op[i] = pack2f(opw, i);
  if (tid < 96) s_small[tid] = me_w1[tid];
  if (tid < 32) s_small[96 + tid] = me_b1[tid];
  if (tid < 64) s_small[128 + tid] = me_b2[tid];
  if (tid < 192) s_small[192 + tid] = ae_w1[tid];
  if (tid < 32) s_small[384 + tid] = ae_b1[tid];
  if (tid < 64) s_small[416 + tid] = ae_b2[tid];
  if (tid < 192) s_small[480 + tid] = ipb[tid];
  if (tid < 64) s_small[672 + tid] = opb[tid];
  if (tid < 64) s_small[736 + tid] = lng[tid];
  if (tid < 64) s_small[800 + tid] = lnb[tid];
  __syncthreads();

  const int wid = tid >> 6, l = tid & 63;
  float* u = &scr[wid * 480];
  // 0..63 enc1-m1/m2 (later CTX) | 64..95 enc1-ac | 96 M1E | 160 M2E | 224 ACE
  // | 288 Q | 352 K1 | 416 K2

  for (int base = blockIdx.x * 4; base < NT; base += 4096) {
    const size_t token = base + wid;
    const size_t ob = token * 12;
    __syncthreads();  // WAR vs previous iteration

    {  // stage 1: encoder hidden layers
      const int half = l >> 5, row = l & 31;
      float i0 = obs[ob + 3 * half + 0];
      float i1 = obs[ob + 3 * half + 1];
      float i2 = obs[ob + 3 * half + 2];
      float acc = s_small[96 + row] + i0 * s_small[row * 3 + 0] +
                  i1 * s_small[row * 3 + 1] + i2 * s_small[row * 3 + 2];
      u[l] = leaky(acc);
      if (l < 32) {
        float a2 = s_small[384 + l];
#pragma unroll
        for (int j = 0; j < 6; ++j) a2 += obs[ob + 6 + j] * s_small[192 + l * 6 + j];
        u[64 + l] = leaky(a2);
      }
    }
    __syncthreads();

    // stage 2: encoder output layers
    float m1e = dot_rot<32>(u + 0, w_me2 + l * 16, l, s_small[128 + l]);
    float m2e = dot_rot<32>(u + 32, w_me2 + l * 16, l, s_small[128 + l]);
    float ace = dot_rot<32>(u + 64, w_ae2 + l * 16, l, s_small[416 + l]);
    u[96 + l] = m1e;
    u[160 + l] = m2e;
    u[224 + l] = ace;
    __syncthreads();

    // stage 3: q,k1,k2,v1,v2
    float k1 = dot_rot<64>(u + 96, w_ip + (64 + l) * 32, l, s_small[480 + 64 + l]);
    float v1 = dot_rot<64>(u + 96, w_ip + (128 + l) * 32, l, s_small[480 + 128 + l]);
    float k2 = dot_rot<64>(u + 160, w_ip + (64 + l) * 32, l, s_small[480 + 64 + l]);
    float v2 = dot_rot<64>(u + 160, w_ip + (128 + l) * 32, l, s_small[480 + 128 + l]);
    float q = dot_rot<64>(u + 224, w_ip + l * 32, l, s_small[480 + l]);
    u[288 + l] = q;
    u[352 + l] = k1;
    u[416 + l] = k2;
    __syncthreads();

    {  // stage 4: 2-key attention per head (HD=16)
      const int hd = l >> 4;
      float s1 = 0.f, s2 = 0.f;
#pragma unroll
      for (int d = 0; d < 16; ++d) {
        float qq = u[288 + hd * 16 + d];
        s1 += qq * u[352 + hd * 16 + d];
        s2 += qq * u[416 + hd * 16 + d];
      }
      s1 *= 0.25f;
      s2 *= 0.25f;
      float mx = fmaxf(s1, s2);
      float e1 = __expf(s1 - mx), e2 = __expf(s2 - mx);
      float a1 = e1 / (e1 + e2);
      u[l] = a1 * v1 + (1.f - a1) * v2;  // CTX
    }
    __syncthreads();

    // out_proj + residual + LayerNorm -> xn (fp32)
    float ao = dot_rot<64>(u + 0, w_op + l * 32, l, s_small[672 + l]);
    float x = ao + ace;
    float s = x, s2s = x * x;
#pragma unroll
    for (int off = 32; off; off >>= 1) {
      s += __shfl_xor(s, off);
      s2s += __shfl_xor(s2s, off);
    }
    float mu = s * (1.f / 64.f);
    float var = s2s * (1.f / 64.f) - mu * mu;
    float rs = rsqrtf(var + 1e-5f);
    xn_out[token * 64 + l] = (x - mu) * rs * s_small[736 + l] + s_small[800 + l];
  }
}

// ---------------- pre_b: xp = xn @ W_ih.T + b_ih  (bf16 out) ----------------
__global__ __launch_bounds__(256) void pre_b(const float* __restrict__ xn_in,
                                             const float* __restrict__ wih,
                                             const float* __restrict__ bih,
                                             bf16* __restrict__ xp) {
  __shared__ __align__(16) uint w[12288];  // 384 rows x 32 uints
  __shared__ float sb[G3];
  __shared__ __align__(16) float xs[4 * 64];
  const int tid = threadIdx.x;
  for (int i = tid; i < 12288; i += 256) w[i] = pack2f(wih, i);
  for (int i = tid; i < G3; i += 256) sb[i] = bih[i];
  __syncthreads();

  const int wid = tid >> 6, l = tid & 63;
  float* x = &xs[wid * 64];
  for (int base = blockIdx.x * 4; base < NT; base += 4096) {
    const size_t token = base + wid;
    __syncthreads();
    x[l] = xn_in[token * 64 + l];
    __syncthreads();
    const size_t outb = token * G3;
#pragma unroll
    for (int r = 0; r < 6; ++r) {
      const int j = r * 64 + l;
      xp[outb + j] = __float2bfloat16(dot_rot<64>(x, w + j * 32, l, sb[j]));
    }
  }
}

// ---------------- gru: in-register gates, 1 raw barrier/step ----------------
// 128 threads per chain; thread j owns W_hh rows {j, 128+j, 256+j} as f16
// pairs in registers; h double-buffered in LDS as packed f16; barrier is
// s_waitcnt lgkmcnt(0)+s_barrier only, so grow global stores never drain on
// the critical path.
__global__ __launch_bounds__(128, 1) void gru_kernel(
    const bf16* __restrict__ xp, const float* __restrict__ hs,
    const float* __restrict__ whh, const float* __restrict__ bhh,
    bf16* __restrict__ gout, float* __restrict__ hlast) {
  __shared__ __align__(16) uint hbuf[2][64];
  const int j = threadIdx.x;
  const int b = blockIdx.x;

  f16x2 wr[64], wz[64], wg[64];
  {
    const float* pr = whh + (size_t)j * HH;
    const float* pz = whh + (size_t)(HH + j) * HH;
    const float* pg = whh + (size_t)(2 * HH + j) * HH;
#pragma unroll
    for (int i = 0; i < 64; ++i) {
      wr[i] = f16x2{(f16)pr[2 * i], (f16)pr[2 * i + 1]};
      wz[i] = f16x2{(f16)pz[2 * i], (f16)pz[2 * i + 1]};
      wg[i] = f16x2{(f16)pg[2 * i], (f16)pg[2 * i + 1]};
    }
  }
  const float br = bhh[j], bz = bhh[HH + j], bg = bhh[2 * HH + j];
  float hprev = hs[b * HH + j];
  if (j < 64) {
    uint lo = (uint)__builtin_bit_cast(unsigned short, (f16)hs[b * HH + 2 * j]);
    uint hi = (uint)__builtin_bit_cast(unsigned short, (f16)hs[b * HH + 2 * j + 1]);
    hbuf[0][j] = lo | (hi << 16);
  }
  __syncthreads();

  const bf16* xrow = xp + (size_t)b * SS * G3 + j;
  bf16* grow = gout + (size_t)b * SS * HH + j;
  float xr_n = __bfloat162float(xrow[0]);
  float xz_n = __bfloat162float(xrow[HH]);
  float xg_n = __bfloat162float(xrow[2 * HH]);

  int cur = 0;
  for (int t = 0; t < SS; ++t) {
    float xr_c = xr_n, xz_c = xz_n, xg_c = xg_n;
    if (t + 1 < SS) {
      const bf16* nx = xrow + (size_t)(t + 1) * G3;
      xr_n = __bfloat162float(nx[0]);
      xz_n = __bfloat162float(nx[HH]);
      xg_n = __bfloat162float(nx[2 * HH]);
    }
    const uint4* hb = (const uint4*)hbuf[cur];
    float ar = 0.f, az = 0.f, ag = 0.f;
#pragma unroll
    for (int i = 0; i < 16; ++i) {
      uint4 hh = hb[i];  // broadcast read (all lanes same address)
      f16x2 h0 = u2h(hh.x), h1 = u2h(hh.y), h2 = u2h(hh.z), h3 = u2h(hh.w);
      ar = __builtin_amdgcn_fdot2(h0, wr[4 * i + 0], ar, false);
      az = __builtin_amdgcn_fdot2(h0, wz[4 * i + 0], az, false);
      ag = __builtin_amdgcn_fdot2(h0, wg[4 * i + 0], ag, false);
      ar = __builtin_amdgcn_fdot2(h1, wr[4 * i + 1], ar, false);
      az = __builtin_amdgcn_fdot2(h1, wz[4 * i + 1], az, false);
      ag = __builtin_amdgcn_fdot2(h1, wg[4 * i + 1], ag, false);
      ar = __builtin_amdgcn_fdot2(h2, wr[4 * i + 2], ar, false);
      az = __builtin_amdgcn_fdot2(h2, wz[4 * i + 2], az, false);
      ag = __builtin_amdgcn_fdot2(h2, wg[4 * i + 2], ag, false);
      ar = __builtin_amdgcn_fdot2(h3, wr[4 * i + 3], ar, false);
      az = __builtin_amdgcn_fdot2(h3, wz[4 * i + 3], az, false);
      ag = __builtin_amdgcn_fdot2(h3, wg[4 * i + 3], ag, false);
    }
    float r = 1.f / (1.f + __expf(-(xr_c + ar + br)));
    float z = 1.f / (1.f + __expf(-(xz_c + az + bz)));
    float gp = xg_c + r * (ag + bg);
    float e = __expf(-2.f * fabsf(gp));
    float th = copysignf((1.f - e) / (1.f + e), gp);
    float hn = (1.f - z) * th + z * hprev;
    hprev = hn;
    ((unsigned short*)hbuf[cur ^ 1])[j] = __builtin_bit_cast(unsigned short, (f16)hn);
    grow[(size_t)t * HH] = __float2bfloat16(hn);
    // LDS-only barrier: do NOT drain vmcnt (keeps grow stores off the path)
    asm volatile("s_waitcnt lgkmcnt(0)\n\ts_barrier" ::: "memory");
    cur ^= 1;
  }
  hlast[b * HH + j] = hprev;
}

// ---------------- mlp0: f0 = leaky(g @ w0.T + b0)  (bf16 out) ---------------
__global__ __launch_bounds__(256) void mlp0(const bf16* __restrict__ gin,
                                            const float* __restrict__ w0b,
                                            const float* __restrict__ b0b,
                                            bf16* __restrict__ f0) {
  __shared__ __align__(16) uint w[8192];  // 128 rows x 64 uints
  __shared__ float bb[HH];
  __shared__ __align__(16) float gs[4 * HH];
  const int tid = threadIdx.x;
  for (int i = tid; i < 8192; i += 256) w[i] = pack2f(w0b, i);
  if (tid < HH) bb[tid] = b0b[tid];
  __syncthreads();

  const int wid = tid >> 6, l = tid & 63;
  float* g = &gs[wid * HH];
  for (int base = blockIdx.x * 4; base < NT; base += 4096) {
    const size_t token = base + wid;
    __syncthreads();
    {
      uint uu = ((const uint*)(gin + token * HH))[l];  // d_ws: aligned
      g[2 * l] = blo(uu);
      g[2 * l + 1] = bhi(uu);
    }
    __syncthreads();
    float A = dot_rot<128>(g, w + l * 64, l, bb[l]);
    float B = dot_rot<128>(g, w + (64 + l) * 64, l, bb[64 + l]);
    f0[token * HH + l] = __float2bfloat16(leaky(A));
    f0[token * HH + 64 + l] = __float2bfloat16(leaky(B));
  }
}

// ---------------- mlp1: value = leaky(f0@w1.T+b1) @ ow.T + ob ---------------
__global__ __launch_bounds__(256) void mlp1(const bf16* __restrict__ f0,
                                            const float* __restrict__ w1b,
                                            const float* __restrict__ b1b,
                                            const float* __restrict__ ow,
                                            const float* __restrict__ obp,
                                            float* __restrict__ value) {
  __shared__ __align__(16) uint w[8192];
  __shared__ float bb[HH];
  __shared__ float ows[HH];
  __shared__ __align__(16) float gs[4 * HH];
  const int tid = threadIdx.x;
  for (int i = tid; i < 8192; i += 256) w[i] = pack2f(w1b, i);
  if (tid < HH) bb[tid] = b1b[tid];
  if (tid < HH) ows[tid] = ow[tid];
  __syncthreads();
  const float obias = obp[0];

  const int wid = tid >> 6, l = tid & 63;
  float* g = &gs[wid * HH];
  for (int base = blockIdx.x * 4; base < NT; base += 4096) {
    const size_t token = base + wid;
    __syncthreads();
    {
      uint uu = ((const uint*)(f0 + token * HH))[l];  // d_ws: aligned
      g[2 * l] = blo(uu);
      g[2 * l + 1] = bhi(uu);
    }
    __syncthreads();
    float A = dot_rot<128>(g, w + l * 64, l, bb[l]);
    float B = dot_rot<128>(g, w + (64 + l) * 64, l, bb[64 + l]);
    float p = leaky(A) * ows[l] + leaky(B) * ows[64 + l];
#pragma unroll
    for (int off = 32; off; off >>= 1) p += __shfl_xor(p, off);
    if (l == 0) value[token] = p + obias;
  }
}

__global__ void fill_sentinel(float* o, int n) {
  for (int i = blockIdx.x * blockDim.x + threadIdx.x; i < n; i += gridDim.x * blockDim.x)
    o[i] = 999.0f;
}

extern "C" void kernel_launch(void* const* d_in, const int* in_sizes, int n_in,
                              void* d_out, int out_size, void* d_ws, size_t ws_size,
                              hipStream_t stream) {
  const float* obs = (const float*)d_in[0];
  const float* hs = (const float*)d_in[1];
  const float* me_w1 = (const float*)d_in[2];
  const float* me_b1 = (const float*)d_in[3];
  const float* me_w2 = (const float*)d_in[4];
  const float* me_b2 = (const float*)d_in[5];
  const float* ae_w1 = (const float*)d_in[6];
  const float* ae_b1 = (const float*)d_in[7];
  const float* ae_w2 = (const float*)d_in[8];
  const float* ae_b2 = (const float*)d_in[9];
  const float* ipw = (const float*)d_in[10];
  const float* ipb = (const float*)d_in[11];
  const float* opw = (const float*)d_in[12];
  const float* opb = (const float*)d_in[13];
  const float* lng = (const float*)d_in[14];
  const float* lnb = (const float*)d_in[15];
  const float* wih = (const float*)d_in[16];
  const float* whh = (const float*)d_in[17];
  const float* bih = (const float*)d_in[18];
  const float* bhh = (const float*)d_in[19];
  const float* w0 = (const float*)d_in[20];
  const float* b0 = (const float*)d_in[21];
  const float* w1 = (const float*)d_in[22];
  const float* b1 = (const float*)d_in[23];
  const float* ow = (const float*)d_in[24];
  const float* ob = (const float*)d_in[25];

  // workspace (128 MiB):
  //  region A [0, 100.66MB): xp bf16 [NT,384]; later f0 bf16 [NT,128]
  //  region B [100.66MB, 134.22MB): xn fp32 [NT,64]; later gout bf16 [NT,128]
  const size_t regA_bytes = (size_t)NT * G3 * sizeof(bf16);
  const size_t regB_bytes = (size_t)NT * 64 * sizeof(float);
  const size_t need = regA_bytes + regB_bytes;  // 134,217,728
  float* out = (float*)d_out;
  if (ws_size < need) {
    fill_sentinel<<<288, 256, 0, stream>>>(out, out_size);
    return;
  }

  char* ws = (char*)d_ws;
  bf16* xp = (bf16*)ws;
  bf16* f0 = (bf16*)ws;
  float* xnf = (float*)(ws + regA_bytes);
  bf16* gout = (bf16*)(ws + regA_bytes);

  pre_a<<<1024, 256, 0, stream>>>(obs, me_w1, me_b1, me_w2, me_b2, ae_w1, ae_b1,
                                  ae_w2, ae_b2, ipw, ipb, opw, opb, lng, lnb, xnf);
  pre_b<<<1024, 256, 0, stream>>>(xnf, wih, bih, xp);
  gru_kernel<<<BB, 128, 0, stream>>>(xp, hs, whh, bhh, gout, out + NT);
  mlp0<<<1024, 256, 0, stream>>>(gout, w0, b0, f0);
  mlp1<<<1024, 256, 0, stream>>>(f0, w1, b1, ow, ob, out);
}